// Round 19
// baseline (101.425 us; speedup 1.0000x reference)
//
#include <hip/hip_runtime.h>

// (B, D, H, W, K) = (64, 256, 32, 32, 512)
#define DIM    256
#define KCODE  512
#define NPOS   1024
#define BATCH  64
#define NPB    64            // positions per block
#define KSTEPS 16            // 16 dims per step (32x32x16 f16 MFMA)
#define EPS    0.001f        // 3-pass residual sigma ~1.5e-5 -> 66 sigma

using f16x8  = __attribute__((ext_vector_type(8))) _Float16;
using f32x16 = __attribute__((ext_vector_type(16))) float;

// workspace layout (bytes)
#define WS_CNT   0
#define WS_ESQ   64
#define WS_WPK   4096                    // 512 KB f16 2-digit packed codebook
#define WS_WT    (4096 + 524288)         // 512 KB wT[K][D] f32
#define WS_LIST  (4096 + 1048576)        // refine list

// ---------------- prep: wpk frag-pack | wT transpose | e_sq fp64 | cnt ----------------
__global__ __launch_bounds__(256) void prep(const float* __restrict__ w,
                                            _Float16* __restrict__ wpk,
                                            float* __restrict__ wT,
                                            float* __restrict__ esq,
                                            int* __restrict__ cnt) {
    __shared__ float ts[32][33];
    __shared__ double sh[8][32];
    const int tid = threadIdx.x;
    const int blk = blockIdx.x;
    if (blk < 128) {
        int gidx = blk * 4 + (tid >> 6);          // 0..511
        int dg = gidx & 1, cg = (gidx >> 1) & 15, t = gidx >> 5;
        int lane = tid & 63, L = lane & 31, h5 = lane >> 5;
        f16x8 out;
#pragma unroll
        for (int j = 0; j < 8; ++j) {
            float v = w[(t * 16 + h5 * 8 + j) * KCODE + cg * 32 + L];
            _Float16 h = (_Float16)v;
            out[j] = dg ? (_Float16)(v - (float)h) : h;
        }
        *(f16x8*)(wpk + (size_t)gidx * 512 + lane * 8) = out;
    } else if (blk < 256) {
        // transpose w[D][K] -> wT[K][D], 32x32 LDS tiles
        int tt = blk - 128;            // 128 tiles = 16 k-tiles x 8 d-tiles
        int kt = tt >> 3, dt = tt & 7;
        int c = tid & 31, rl = tid >> 5;
#pragma unroll
        for (int r = 0; r < 4; ++r) {
            int dloc = rl * 4 + r;
            ts[dloc][c] = w[(dt * 32 + dloc) * KCODE + kt * 32 + c];
        }
        __syncthreads();
#pragma unroll
        for (int r = 0; r < 4; ++r) {
            int kloc = rl * 4 + r;
            wT[(size_t)(kt * 32 + kloc) * DIM + dt * 32 + c] = ts[c][kloc];
        }
    } else if (blk < 272) {
        int idx = blk - 256;           // 0..15
        int code = idx * 32 + (tid & 31);
        int sl = tid >> 5;
        double s = 0.0;
        for (int d = sl * 32; d < sl * 32 + 32; ++d) {
            double v = (double)w[d * KCODE + code];
            s = fma(v, v, s);
        }
        sh[sl][tid & 31] = s;
        __syncthreads();
        if (tid < 32) {
            double t = 0.0;
            for (int i = 0; i < 8; ++i) t += sh[i][tid];
            esq[idx * 32 + tid] = (float)t;
        }
    } else {
        if (tid == 0) *cnt = 0;
    }
}

// ---------------- main: B (2-digit) LDS-resident, A streamed to regs, 3-pass f16 MFMA ----------------
// round-14 K-loop; fused single-pass top2+argmin epilogue (no rescan, 2 fewer barriers)
__global__ __launch_bounds__(512, 4) void vq_main(
    const float* __restrict__ x, const _Float16* __restrict__ wpk,
    const float* __restrict__ esq, const float* __restrict__ wT,
    float* __restrict__ quant, float* __restrict__ argm,
    int* __restrict__ cnt, int* __restrict__ list) {

    __shared__ __align__(128) unsigned char smem[67584];
    unsigned char* Bt = smem;                    // 64 KB
    float* esq_s  = (float*)(smem + 65536);      // 2 KB (live whole kernel)
    // overlays (valid after post-K-loop barrier):
    float* red1   = (float*)smem;                // 8*64*4 = 2048
    float* red2   = (float*)(smem + 2048);       // 2048
    int*   redi   = (int*)(smem + 4096);         // 2048
    float* qt     = (float*)(smem + 6144);       // 64*65*4 = 16640 -> ends 22784
    int*   idxbuf = (int*)(smem + 23040);        // 256

    const int tid  = threadIdx.x;
    const int wv   = tid >> 6;        // wave = code group: codes [wv*64, wv*64+64)
    const int lane = tid & 63;
    const int L    = lane & 31;
    const int h5   = lane >> 5;

    const int p0 = blockIdx.x * NPB;
    const int b  = p0 >> 10;
    const int n0 = p0 & (NPOS - 1);

    const int pos = tid & 63;
    const int tg  = tid >> 6;         // 0..7

    esq_s[tid] = esq[tid];

    // ---- stage B once: x f32 -> 2-digit f16, frag-ready dense layout ----
#pragma unroll
    for (int tt = 0; tt < 2; ++tt) {
        int t = tg * 2 + tt;
#pragma unroll
        for (int hh = 0; hh < 2; ++hh) {
            const float* xp = x + ((size_t)b * DIM + t * 16 + hh * 8) * NPOS + n0 + pos;
            f16x8 vh, vl;
#pragma unroll
            for (int j = 0; j < 8; ++j) {
                float v = xp[(size_t)j * NPOS];
                _Float16 h = (_Float16)v;
                vh[j] = h;
                vl[j] = (_Float16)(v - (float)h);
            }
            *(f16x8*)(Bt + ((((t * 2 + hh) * 2) + 0) * NPB + pos) * 16) = vh;
            *(f16x8*)(Bt + ((((t * 2 + hh) * 2) + 1) * NPB + pos) * 16) = vl;
        }
    }
    __syncthreads();

    // ---- K-loop: no barriers, register dataflow only ----
    f32x16 acc[2][2] = {};

#pragma unroll
    for (int t = 0; t < KSTEPS; ++t) {
        f16x8 Ah[2][2];   // [fm][w-digit]
#pragma unroll
        for (int fm = 0; fm < 2; ++fm)
#pragma unroll
            for (int dg = 0; dg < 2; ++dg)
                Ah[fm][dg] = *(const f16x8*)(
                    wpk + (size_t)(((t * 16 + wv * 2 + fm) * 2 + dg) * 64 + lane) * 8);
        f16x8 Bf[2][2];   // [fn][x-digit]
#pragma unroll
        for (int fn = 0; fn < 2; ++fn)
#pragma unroll
            for (int dg = 0; dg < 2; ++dg)
                Bf[fn][dg] = *(const f16x8*)(
                    Bt + ((((t * 2 + h5) * 2) + dg) * NPB + fn * 32 + L) * 16);
        // pass-major: 3 passes of 4 independent acc chains (dep distance 4)
#pragma unroll
        for (int fm = 0; fm < 2; ++fm)
#pragma unroll
            for (int fn = 0; fn < 2; ++fn)
                acc[fm][fn] = __builtin_amdgcn_mfma_f32_32x32x16_f16(Ah[fm][0], Bf[fn][0], acc[fm][fn], 0, 0, 0);
#pragma unroll
        for (int fm = 0; fm < 2; ++fm)
#pragma unroll
            for (int fn = 0; fn < 2; ++fn)
                acc[fm][fn] = __builtin_amdgcn_mfma_f32_32x32x16_f16(Ah[fm][1], Bf[fn][0], acc[fm][fn], 0, 0, 0);
#pragma unroll
        for (int fm = 0; fm < 2; ++fm)
#pragma unroll
            for (int fn = 0; fn < 2; ++fn)
                acc[fm][fn] = __builtin_amdgcn_mfma_f32_32x32x16_f16(Ah[fm][0], Bf[fn][1], acc[fm][fn], 0, 0, 0);
    }
    __syncthreads();                  // B reads done -> overlays safe

    // ---- epilogue: fused score + top-2 + argmin (min-code tie-break), single pass ----
    float v1[2] = {3.4e38f, 3.4e38f};
    float v2[2] = {3.4e38f, 3.4e38f};
    int   i1[2] = {0x7FFFFFFF, 0x7FFFFFFF};
#pragma unroll
    for (int fm = 0; fm < 2; ++fm)
#pragma unroll
        for (int r = 0; r < 16; ++r) {
            int code = wv * 64 + fm * 32 + (r & 3) + 8 * (r >> 2) + 4 * h5;
            float e = esq_s[code];
#pragma unroll
            for (int fn = 0; fn < 2; ++fn) {
                float s = fmaf(-2.f, acc[fm][fn][r], e);
                bool lt = s < v1[fn];
                bool eq = s == v1[fn];
                i1[fn] = lt ? code : (eq ? min(i1[fn], code) : i1[fn]);
                float hi = fmaxf(s, v1[fn]);
                v1[fn] = fminf(s, v1[fn]);
                v2[fn] = fminf(v2[fn], hi);
            }
        }
    // h5-pair merge (lane ^ 32): merge (v1,i1,v2) triples
#pragma unroll
    for (int fn = 0; fn < 2; ++fn) {
        float o1 = __shfl_xor(v1[fn], 32, 64);
        float o2 = __shfl_xor(v2[fn], 32, 64);
        int   oi = __shfl_xor(i1[fn], 32, 64);
        float mx = fmaxf(v1[fn], o1);
        v2[fn] = fminf(fminf(v2[fn], o2), mx);
        bool lt = o1 < v1[fn];
        bool eq = o1 == v1[fn];
        i1[fn] = lt ? oi : (eq ? min(i1[fn], oi) : i1[fn]);
        v1[fn] = fminf(v1[fn], o1);
        if (h5 == 0) {
            red1[wv * NPB + fn * 32 + L] = v1[fn];
            red2[wv * NPB + fn * 32 + L] = v2[fn];
            redi[wv * NPB + fn * 32 + L] = i1[fn];
        }
    }
    __syncthreads();
    if (tid < NPB) {
        float g1 = red1[tid], g2 = red2[tid];
        int   gi = redi[tid];
#pragma unroll
        for (int wvi = 1; wvi < 8; ++wvi) {
            float a1 = red1[wvi * NPB + tid], a2 = red2[wvi * NPB + tid];
            int   ai = redi[wvi * NPB + tid];
            float mx = fmaxf(g1, a1);
            g2 = fminf(fminf(g2, a2), mx);
            bool lt = a1 < g1;
            bool eq = a1 == g1;
            gi = lt ? ai : (eq ? min(gi, ai) : gi);
            g1 = fminf(g1, a1);
        }
        idxbuf[tid] = gi;
        argm[(size_t)b * NPOS + n0 + tid] = (float)gi;
        if (g2 - g1 < EPS) {          // near-tie under approximation: exact recheck
            int slot = atomicAdd(cnt, 1);
            list[slot] = p0 + tid;
        }
    }
    __syncthreads();

    // ---- quant write: coalesced wT row-copies via padded LDS tile ----
    for (int ch = 0; ch < 4; ++ch) {             // 4 chunks of 64 dims
#pragma unroll
        for (int it = 0; it < 8; ++it) {
            int pp = it * 8 + wv;
            int bi = idxbuf[pp];
            qt[pp * 65 + lane] = wT[(size_t)bi * DIM + ch * 64 + lane];
        }
        __syncthreads();
#pragma unroll
        for (int i = 0; i < 8; ++i) {
            int d = ch * 64 + i * 8 + tg;
            quant[((size_t)b * DIM + d) * NPOS + n0 + pos] = qt[pos * 65 + i * 8 + tg];
        }
        __syncthreads();
    }
}

// ---------------- refine: one block per flagged position, exact fp64 ----------------
__global__ __launch_bounds__(512) void refine(const float* __restrict__ x,
                                              const float* __restrict__ w,
                                              float* __restrict__ quant,
                                              float* __restrict__ argm,
                                              const int* __restrict__ cnt,
                                              const int* __restrict__ list) {
    __shared__ float  xs[DIM];
    __shared__ double dv[512];
    __shared__ int    di[512];
    const int tid = threadIdx.x;
    const int n = *cnt;
    for (int i = blockIdx.x; i < n; i += gridDim.x) {
        const int p = list[i];
        const size_t pb = (size_t)(p >> 10), pn = (size_t)(p & (NPOS - 1));
        if (tid < DIM) xs[tid] = x[(pb * DIM + tid) * NPOS + pn];
        __syncthreads();
        double acc = 0.0, sw = 0.0;
#pragma unroll 8
        for (int d = 0; d < DIM; ++d) {
            double wv = (double)w[d * KCODE + tid];
            double xv = (double)xs[d];
            acc = fma(wv, xv, acc);
            sw  = fma(wv, wv, sw);
        }
        dv[tid] = sw - 2.0 * acc;
        di[tid] = tid;
        __syncthreads();
        for (int off = 256; off > 0; off >>= 1) {
            if (tid < off) {
                double ov = dv[tid + off]; int oi = di[tid + off];
                if (ov < dv[tid] || (ov == dv[tid] && oi < di[tid])) { dv[tid] = ov; di[tid] = oi; }
            }
            __syncthreads();
        }
        const int bsel = di[0];
        if (tid == 0) argm[pb * NPOS + pn] = (float)bsel;
        if (tid < DIM) quant[(pb * DIM + tid) * NPOS + pn] = w[tid * KCODE + bsel];
        __syncthreads();
    }
}

extern "C" void kernel_launch(void* const* d_in, const int* in_sizes, int n_in,
                              void* d_out, int out_size, void* d_ws, size_t ws_size,
                              hipStream_t stream) {
    (void)in_sizes; (void)n_in; (void)out_size; (void)ws_size;
    const float* x = (const float*)d_in[0];
    const float* w = (const float*)d_in[1];
    float* quant = (float*)d_out;
    float* argm  = quant + (size_t)BATCH * DIM * NPOS;
    char* ws = (char*)d_ws;
    int*      cnt = (int*)(ws + WS_CNT);
    float*    esq = (float*)(ws + WS_ESQ);
    _Float16* wpk = (_Float16*)(ws + WS_WPK);
    float*    wT  = (float*)(ws + WS_WT);
    int*      list = (int*)(ws + WS_LIST);

    prep<<<273, 256, 0, stream>>>(w, wpk, wT, esq, cnt);
    vq_main<<<(BATCH * NPOS) / NPB, 512, 0, stream>>>(x, wpk, esq, wT, quant, argm, cnt, list);
    refine<<<2048, 512, 0, stream>>>(x, w, quant, argm, cnt, list);
}

// Round 20
// 95.310 us; speedup vs baseline: 1.0642x; 1.0642x over previous
//
#include <hip/hip_runtime.h>

// (B, D, H, W, K) = (64, 256, 32, 32, 512)
#define DIM    256
#define KCODE  512
#define NPOS   1024
#define BATCH  64
#define NPB    64            // positions per block
#define KSTEPS 16            // 16 dims per step (32x32x16 f16 MFMA)
#define EPS    0.001f        // 3-pass residual sigma ~1.5e-5 -> 66 sigma margin

using f16x8  = __attribute__((ext_vector_type(8))) _Float16;
using f32x16 = __attribute__((ext_vector_type(16))) float;

// workspace layout (bytes)
#define WS_CNT   0
#define WS_ESQ   64
#define WS_WPK   4096                    // 512 KB f16 2-digit packed codebook
#define WS_WT    (4096 + 524288)         // 512 KB wT[K][D] f32
#define WS_LIST  (4096 + 1048576)        // refine list

// ---------------- prep: wpk frag-pack | wT transpose | e_sq fp64 | cnt ----------------
__global__ __launch_bounds__(256) void prep(const float* __restrict__ w,
                                            _Float16* __restrict__ wpk,
                                            float* __restrict__ wT,
                                            float* __restrict__ esq,
                                            int* __restrict__ cnt) {
    __shared__ float ts[32][33];
    __shared__ double sh[8][32];
    const int tid = threadIdx.x;
    const int blk = blockIdx.x;
    if (blk < 128) {
        int gidx = blk * 4 + (tid >> 6);          // 0..511
        int dg = gidx & 1, cg = (gidx >> 1) & 15, t = gidx >> 5;
        int lane = tid & 63, L = lane & 31, h5 = lane >> 5;
        f16x8 out;
#pragma unroll
        for (int j = 0; j < 8; ++j) {
            float v = w[(t * 16 + h5 * 8 + j) * KCODE + cg * 32 + L];
            _Float16 h = (_Float16)v;
            out[j] = dg ? (_Float16)(v - (float)h) : h;
        }
        *(f16x8*)(wpk + (size_t)gidx * 512 + lane * 8) = out;
    } else if (blk < 256) {
        // transpose w[D][K] -> wT[K][D], 32x32 LDS tiles
        int tt = blk - 128;            // 128 tiles = 16 k-tiles x 8 d-tiles
        int kt = tt >> 3, dt = tt & 7;
        int c = tid & 31, rl = tid >> 5;
#pragma unroll
        for (int r = 0; r < 4; ++r) {
            int dloc = rl * 4 + r;
            ts[dloc][c] = w[(dt * 32 + dloc) * KCODE + kt * 32 + c];
        }
        __syncthreads();
#pragma unroll
        for (int r = 0; r < 4; ++r) {
            int kloc = rl * 4 + r;
            wT[(size_t)(kt * 32 + kloc) * DIM + dt * 32 + c] = ts[c][kloc];
        }
    } else if (blk < 272) {
        int idx = blk - 256;           // 0..15
        int code = idx * 32 + (tid & 31);
        int sl = tid >> 5;
        double s = 0.0;
        for (int d = sl * 32; d < sl * 32 + 32; ++d) {
            double v = (double)w[d * KCODE + code];
            s = fma(v, v, s);
        }
        sh[sl][tid & 31] = s;
        __syncthreads();
        if (tid < 32) {
            double t = 0.0;
            for (int i = 0; i < 8; ++i) t += sh[i][tid];
            esq[idx * 32 + tid] = (float)t;
        }
    } else {
        if (tid == 0) *cnt = 0;
    }
}

// ---------------- main: B (2-digit) LDS-resident, A streamed to regs, 3-pass f16 MFMA ----------------
// round-14 kernel verbatim (best measured: 76.0 us) -- only EPS differs via macro
__global__ __launch_bounds__(512, 4) void vq_main(
    const float* __restrict__ x, const _Float16* __restrict__ wpk,
    const float* __restrict__ esq, const float* __restrict__ wT,
    float* __restrict__ quant, float* __restrict__ argm,
    int* __restrict__ cnt, int* __restrict__ list) {

    __shared__ __align__(128) unsigned char smem[67584];
    unsigned char* Bt = smem;                    // 64 KB
    float* esq_s  = (float*)(smem + 65536);      // 2 KB (live whole kernel)
    // overlays (valid after post-K-loop barrier):
    float* red1   = (float*)smem;                // 8*64*4 = 2048
    float* red2   = (float*)(smem + 2048);       // 2048
    int*   redi   = (int*)(smem + 4096);         // 2048
    float* qt     = (float*)(smem + 6144);       // 64*65*4 = 16640 -> ends 22784
    float* bestv  = (float*)(smem + 22784);      // 256
    int*   idxbuf = (int*)(smem + 23040);        // 256

    const int tid  = threadIdx.x;
    const int wv   = tid >> 6;        // wave = code group: codes [wv*64, wv*64+64)
    const int lane = tid & 63;
    const int L    = lane & 31;
    const int h5   = lane >> 5;

    const int p0 = blockIdx.x * NPB;
    const int b  = p0 >> 10;
    const int n0 = p0 & (NPOS - 1);

    const int pos = tid & 63;
    const int tg  = tid >> 6;         // 0..7

    esq_s[tid] = esq[tid];

    // ---- stage B once: x f32 -> 2-digit f16, frag-ready dense layout ----
#pragma unroll
    for (int tt = 0; tt < 2; ++tt) {
        int t = tg * 2 + tt;
#pragma unroll
        for (int hh = 0; hh < 2; ++hh) {
            const float* xp = x + ((size_t)b * DIM + t * 16 + hh * 8) * NPOS + n0 + pos;
            f16x8 vh, vl;
#pragma unroll
            for (int j = 0; j < 8; ++j) {
                float v = xp[(size_t)j * NPOS];
                _Float16 h = (_Float16)v;
                vh[j] = h;
                vl[j] = (_Float16)(v - (float)h);
            }
            *(f16x8*)(Bt + ((((t * 2 + hh) * 2) + 0) * NPB + pos) * 16) = vh;
            *(f16x8*)(Bt + ((((t * 2 + hh) * 2) + 1) * NPB + pos) * 16) = vl;
        }
    }
    __syncthreads();

    // ---- K-loop: no barriers, register dataflow only ----
    f32x16 acc[2][2] = {};

#pragma unroll
    for (int t = 0; t < KSTEPS; ++t) {
        f16x8 Ah[2][2];   // [fm][w-digit]
#pragma unroll
        for (int fm = 0; fm < 2; ++fm)
#pragma unroll
            for (int dg = 0; dg < 2; ++dg)
                Ah[fm][dg] = *(const f16x8*)(
                    wpk + (size_t)(((t * 16 + wv * 2 + fm) * 2 + dg) * 64 + lane) * 8);
        f16x8 Bf[2][2];   // [fn][x-digit]
#pragma unroll
        for (int fn = 0; fn < 2; ++fn)
#pragma unroll
            for (int dg = 0; dg < 2; ++dg)
                Bf[fn][dg] = *(const f16x8*)(
                    Bt + ((((t * 2 + h5) * 2) + dg) * NPB + fn * 32 + L) * 16);
        // pass-major: 3 passes of 4 independent acc chains (dep distance 4)
#pragma unroll
        for (int fm = 0; fm < 2; ++fm)
#pragma unroll
            for (int fn = 0; fn < 2; ++fn)
                acc[fm][fn] = __builtin_amdgcn_mfma_f32_32x32x16_f16(Ah[fm][0], Bf[fn][0], acc[fm][fn], 0, 0, 0);
#pragma unroll
        for (int fm = 0; fm < 2; ++fm)
#pragma unroll
            for (int fn = 0; fn < 2; ++fn)
                acc[fm][fn] = __builtin_amdgcn_mfma_f32_32x32x16_f16(Ah[fm][1], Bf[fn][0], acc[fm][fn], 0, 0, 0);
#pragma unroll
        for (int fm = 0; fm < 2; ++fm)
#pragma unroll
            for (int fn = 0; fn < 2; ++fn)
                acc[fm][fn] = __builtin_amdgcn_mfma_f32_32x32x16_f16(Ah[fm][0], Bf[fn][1], acc[fm][fn], 0, 0, 0);
    }
    __syncthreads();                  // B reads done -> overlays safe

    // ---- epilogue: score = e^2 - 2*cross, per-lane top-2, block argmin ----
    float v1[2] = {3.4e38f, 3.4e38f};
    float v2[2] = {3.4e38f, 3.4e38f};
#pragma unroll
    for (int fm = 0; fm < 2; ++fm)
#pragma unroll
        for (int r = 0; r < 16; ++r) {
            int code = wv * 64 + fm * 32 + (r & 3) + 8 * (r >> 2) + 4 * h5;
            float e = esq_s[code];
#pragma unroll
            for (int fn = 0; fn < 2; ++fn) {
                float s = fmaf(-2.f, acc[fm][fn][r], e);
                acc[fm][fn][r] = s;
                float lo_ = fminf(s, v1[fn]);
                float hi_ = fmaxf(s, v1[fn]);
                v1[fn] = lo_;
                v2[fn] = fminf(v2[fn], hi_);
            }
        }
#pragma unroll
    for (int fn = 0; fn < 2; ++fn) {
        float o1 = __shfl_xor(v1[fn], 32, 64);
        float o2 = __shfl_xor(v2[fn], 32, 64);
        float mn = fminf(v1[fn], o1);
        float mx = fmaxf(v1[fn], o1);
        v1[fn] = mn;
        v2[fn] = fminf(fminf(v2[fn], o2), mx);
        if (h5 == 0) { red1[wv * NPB + fn * 32 + L] = v1[fn]; red2[wv * NPB + fn * 32 + L] = v2[fn]; }
    }
    __syncthreads();
    if (tid < NPB) {
        float g1 = red1[tid], g2 = red2[tid];
#pragma unroll
        for (int wvi = 1; wvi < 8; ++wvi) {
            float a1 = red1[wvi * NPB + tid], a2 = red2[wvi * NPB + tid];
            float mn = fminf(g1, a1), mx = fmaxf(g1, a1);
            g1 = mn; g2 = fminf(fminf(g2, a2), mx);
        }
        bestv[tid] = g1;
        if (g2 - g1 < EPS) {          // near-tie under approximation: exact recheck
            int slot = atomicAdd(cnt, 1);
            list[slot] = p0 + tid;
        }
    }
    __syncthreads();
    // rescan for argmin index (min code among exact matches)
#pragma unroll
    for (int fn = 0; fn < 2; ++fn) {
        float tgt = bestv[fn * 32 + L];
        int cand = 0x7FFFFFFF;
#pragma unroll
        for (int fm = 0; fm < 2; ++fm)
#pragma unroll
            for (int r = 0; r < 16; ++r) {
                int code = wv * 64 + fm * 32 + (r & 3) + 8 * (r >> 2) + 4 * h5;
                if (acc[fm][fn][r] == tgt) cand = min(cand, code);
            }
        int oc = __shfl_xor(cand, 32, 64);
        cand = min(cand, oc);
        if (h5 == 0) redi[wv * NPB + fn * 32 + L] = cand;
    }
    __syncthreads();
    if (tid < NPB) {
        int bi = redi[tid];
#pragma unroll
        for (int wvi = 1; wvi < 8; ++wvi) bi = min(bi, redi[wvi * NPB + tid]);
        idxbuf[tid] = bi;
        argm[(size_t)b * NPOS + n0 + tid] = (float)bi;
    }
    __syncthreads();

    // ---- quant write: coalesced wT row-copies via padded LDS tile ----
    for (int ch = 0; ch < 4; ++ch) {             // 4 chunks of 64 dims
#pragma unroll
        for (int it = 0; it < 8; ++it) {
            int pp = it * 8 + wv;
            int bi = idxbuf[pp];
            qt[pp * 65 + lane] = wT[(size_t)bi * DIM + ch * 64 + lane];
        }
        __syncthreads();
#pragma unroll
        for (int i = 0; i < 8; ++i) {
            int d = ch * 64 + i * 8 + tg;
            quant[((size_t)b * DIM + d) * NPOS + n0 + pos] = qt[pos * 65 + i * 8 + tg];
        }
        __syncthreads();
    }
}

// ---------------- refine: one block per flagged position, exact fp64 ----------------
__global__ __launch_bounds__(512) void refine(const float* __restrict__ x,
                                              const float* __restrict__ w,
                                              float* __restrict__ quant,
                                              float* __restrict__ argm,
                                              const int* __restrict__ cnt,
                                              const int* __restrict__ list) {
    __shared__ float  xs[DIM];
    __shared__ double dv[512];
    __shared__ int    di[512];
    const int tid = threadIdx.x;
    const int n = *cnt;
    for (int i = blockIdx.x; i < n; i += gridDim.x) {
        const int p = list[i];
        const size_t pb = (size_t)(p >> 10), pn = (size_t)(p & (NPOS - 1));
        if (tid < DIM) xs[tid] = x[(pb * DIM + tid) * NPOS + pn];
        __syncthreads();
        double acc = 0.0, sw = 0.0;
#pragma unroll 8
        for (int d = 0; d < DIM; ++d) {
            double wv = (double)w[d * KCODE + tid];
            double xv = (double)xs[d];
            acc = fma(wv, xv, acc);
            sw  = fma(wv, wv, sw);
        }
        dv[tid] = sw - 2.0 * acc;
        di[tid] = tid;
        __syncthreads();
        for (int off = 256; off > 0; off >>= 1) {
            if (tid < off) {
                double ov = dv[tid + off]; int oi = di[tid + off];
                if (ov < dv[tid] || (ov == dv[tid] && oi < di[tid])) { dv[tid] = ov; di[tid] = oi; }
            }
            __syncthreads();
        }
        const int bsel = di[0];
        if (tid == 0) argm[pb * NPOS + pn] = (float)bsel;
        if (tid < DIM) quant[(pb * DIM + tid) * NPOS + pn] = w[tid * KCODE + bsel];
        __syncthreads();
    }
}

extern "C" void kernel_launch(void* const* d_in, const int* in_sizes, int n_in,
                              void* d_out, int out_size, void* d_ws, size_t ws_size,
                              hipStream_t stream) {
    (void)in_sizes; (void)n_in; (void)out_size; (void)ws_size;
    const float* x = (const float*)d_in[0];
    const float* w = (const float*)d_in[1];
    float* quant = (float*)d_out;
    float* argm  = quant + (size_t)BATCH * DIM * NPOS;
    char* ws = (char*)d_ws;
    int*      cnt = (int*)(ws + WS_CNT);
    float*    esq = (float*)(ws + WS_ESQ);
    _Float16* wpk = (_Float16*)(ws + WS_WPK);
    float*    wT  = (float*)(ws + WS_WT);
    int*      list = (int*)(ws + WS_LIST);

    prep<<<273, 256, 0, stream>>>(w, wpk, wT, esq, cnt);
    vq_main<<<(BATCH * NPOS) / NPB, 512, 0, stream>>>(x, wpk, esq, wT, quant, argm, cnt, list);
    refine<<<256, 512, 0, stream>>>(x, w, quant, argm, cnt, list);
}